// Round 16
// baseline (280.686 us; speedup 1.0000x reference)
//
#include <hip/hip_runtime.h>

// ---------------------------------------------------------------------------
// Batch-inner LeNet: lane = image, activations in [feature][N] layout.
// R16 delta vs R15 (best, 269us): conv1/conv2 inner loops emit
// v_pk_fma_f32 via inline asm (2 fp32 FMA/lane/instr). Weight operand is
// wave-uniform -> duplicated into a 64-bit SGPR pair on the scalar pipe
// (legal single-SGPR VALU source), so the vector pipe sees ONLY pk-FMAs.
// Memory pattern, grids, numerics identical (pk halves = IEEE fp32 FMA).
// ---------------------------------------------------------------------------

typedef __attribute__((ext_vector_type(2))) float f32x2;

__device__ __forceinline__ int xcd_swizzle(int orig, int nwg) {
    // m204 bijective: xcd = orig%8 gets a contiguous newid range.
    int xcd = orig & 7, q = nwg >> 3, r = nwg & 7;
    int base = (xcd < r) ? xcd * (q + 1) : r * (q + 1) + (xcd - r) * q;
    return base + (orig >> 3);
}

// duplicate a uniform fp32 into both halves of a 64-bit scalar (SGPR pair)
__device__ __forceinline__ unsigned long long dupw(float w) {
    unsigned int b = __float_as_uint(w);
    return ((unsigned long long)b << 32) | b;
}

// d = a * w + c  per 32-bit half; w broadcast from SGPR pair
__device__ __forceinline__ f32x2 pk_fma(f32x2 a, unsigned long long wp, f32x2 c) {
    f32x2 d;
    asm("v_pk_fma_f32 %0, %1, %2, %3" : "=v"(d) : "v"(a), "s"(wp), "v"(c));
    return d;
}

// Transpose x[nc,784] -> xt[1024,nc] (zero-padded 32x32 image layout).
// grid = (16, nc/64).
__global__ __launch_bounds__(256) void transpose_x(
    const float* __restrict__ x, float* __restrict__ xt, int nc)
{
    __shared__ float t[64][65];
    const int tx = threadIdx.x & 63, ty = threadIdx.x >> 6;  // ty 0..3
    const int p0 = blockIdx.x * 64, n0 = blockIdx.y * 64;
    #pragma unroll
    for (int rr = 0; rr < 16; ++rr) {
        int nl = rr * 4 + ty;
        int pp = p0 + tx;              // padded pixel 0..1023
        int pr = pp >> 5, pc = pp & 31;
        float v = 0.f;
        if (pr >= 2 && pr < 30 && pc >= 2 && pc < 30)
            v = x[(size_t)(n0 + nl) * 784 + (pr - 2) * 28 + (pc - 2)];
        t[tx][nl] = v;
    }
    __syncthreads();
    #pragma unroll
    for (int rr = 0; rr < 16; ++rr) {
        int pl = rr * 4 + ty;
        xt[(size_t)(p0 + pl) * nc + n0 + tx] = t[pl][tx];
    }
}

// conv1(pad2)+relu+pool. Flat grid = 196*(nc/512); 2 consecutive images per
// thread; pk-FMA quads. Weights via scalar pipe (dup'd SGPR pairs).
__global__ __launch_bounds__(256, 1) void conv1_bt(
    const float* __restrict__ xt, const float* __restrict__ c1w,
    const float* __restrict__ c1b, float* __restrict__ p1t, int nc)
{
    const int newid = xcd_swizzle(blockIdx.x, gridDim.x);
    const int grp = newid / 196, pos = newid - grp * 196;
    const int py = pos / 14, px = pos - py * 14;
    const int img = grp * 512 + threadIdx.x * 2;
    const int pbase = (2 * py) * 32 + 2 * px; // top-left of 6x6 in padded img

    f32x2 p[36];
    #pragma unroll
    for (int r = 0; r < 6; ++r)
        #pragma unroll
        for (int cc = 0; cc < 6; ++cc)
            p[r * 6 + cc] =
                *(const f32x2*)&xt[(size_t)(pbase + r * 32 + cc) * nc + img];

    #pragma unroll
    for (int ch = 0; ch < 6; ++ch) {
        const float* wp = c1w + ch * 25;     // uniform -> s_load
        float b = c1b[ch];
        f32x2 a00 = (f32x2)(b), a01 = (f32x2)(b);
        f32x2 a10 = (f32x2)(b), a11 = (f32x2)(b);
        #pragma unroll
        for (int ky = 0; ky < 5; ++ky)
        #pragma unroll
        for (int kx = 0; kx < 5; ++kx) {
            unsigned long long wpp = dupw(wp[ky * 5 + kx]);
            a00 = pk_fma(p[ky * 6 + kx],       wpp, a00);
            a01 = pk_fma(p[ky * 6 + kx + 1],   wpp, a01);
            a10 = pk_fma(p[(ky + 1) * 6 + kx], wpp, a10);
            a11 = pk_fma(p[(ky + 1) * 6 + kx + 1], wpp, a11);
        }
        f32x2 o2;
        o2.x = fmaxf(fmaxf(fmaxf(a00.x, a01.x), fmaxf(a10.x, a11.x)), 0.f);
        o2.y = fmaxf(fmaxf(fmaxf(a00.y, a01.y), fmaxf(a10.y, a11.y)), 0.f);
        *(f32x2*)&p1t[(size_t)(ch * 196 + pos) * nc + img] = o2;
    }
}

// conv2(valid)+relu+pool: 2 images/thread, 8 oc/block (pass in blockIdx),
// pk-FMA quads. Flat grid = 50*(nc/512), XCD-swizzled (group window 2.4 MB
// <= 4 MB L2). Feature order ch*25 + qy*5 + qx.
__global__ __launch_bounds__(256, 1) void conv2_bt(
    const float* __restrict__ p1t, const float* __restrict__ c2w,
    const float* __restrict__ c2b, float* __restrict__ ht, int nc)
{
    const int newid = xcd_swizzle(blockIdx.x, gridDim.x);
    const int grp = newid / 50, rem = newid - grp * 50;
    const int pass = rem / 25, pos = rem - pass * 25;
    const int qy = pos / 5, qx = pos - qy * 5;
    const int img = grp * 512 + threadIdx.x * 2;
    const int y0 = 2 * qy, x0 = 2 * qx;

    f32x2 acc[32];                      // [o8][quad], 2 imgs packed
    #pragma unroll
    for (int i = 0; i < 32; ++i) acc[i] = (f32x2)(0.f);

    #pragma unroll 1
    for (int ci = 0; ci < 6; ++ci) {
        f32x2 pa[36];
        #pragma unroll
        for (int r = 0; r < 6; ++r)
            #pragma unroll
            for (int cc = 0; cc < 6; ++cc)
                pa[r * 6 + cc] = *(const f32x2*)
                    &p1t[(size_t)(ci * 196 + (y0 + r) * 14 + x0 + cc) * nc + img];
        #pragma unroll
        for (int o8 = 0; o8 < 8; ++o8) {
            const float* wp = c2w + ((pass * 8 + o8) * 6 + ci) * 25;
            #pragma unroll
            for (int ky = 0; ky < 5; ++ky)
            #pragma unroll
            for (int kx = 0; kx < 5; ++kx) {
                unsigned long long wpp = dupw(wp[ky * 5 + kx]);
                acc[o8*4+0] = pk_fma(pa[ky*6+kx],       wpp, acc[o8*4+0]);
                acc[o8*4+1] = pk_fma(pa[ky*6+kx+1],     wpp, acc[o8*4+1]);
                acc[o8*4+2] = pk_fma(pa[(ky+1)*6+kx],   wpp, acc[o8*4+2]);
                acc[o8*4+3] = pk_fma(pa[(ky+1)*6+kx+1], wpp, acc[o8*4+3]);
            }
        }
    }
    #pragma unroll
    for (int o8 = 0; o8 < 8; ++o8) {
        int oc = pass * 8 + o8;
        float b = c2b[oc];
        float mx = fmaxf(fmaxf(acc[o8*4+0].x, acc[o8*4+1].x),
                         fmaxf(acc[o8*4+2].x, acc[o8*4+3].x)) + b;
        float my = fmaxf(fmaxf(acc[o8*4+0].y, acc[o8*4+1].y),
                         fmaxf(acc[o8*4+2].y, acc[o8*4+3].y)) + b;
        f32x2 o2;
        o2.x = fmaxf(mx, 0.f);
        o2.y = fmaxf(my, 0.f);
        *(f32x2*)&ht[(size_t)(oc * 25 + pos) * nc + img] = o2;
    }
}

// fc1: a1t[o][n] = relu(sum_k ht[k][n]*f1w[o][k] + b). 2 img/thread (f32x2),
// 8 outs/block-group. Flat grid = 15*(nc/512), XCD-swizzled.
__global__ __launch_bounds__(256) void fc1_bt(
    const float* __restrict__ ht, const float* __restrict__ f1w,
    const float* __restrict__ f1b, float* __restrict__ a1t, int nc)
{
    const int newid = xcd_swizzle(blockIdx.x, gridDim.x);
    const int grp = newid / 15, og = newid - grp * 15;
    const int img = grp * 512 + threadIdx.x * 2;
    const float* wb = f1w + og * 8 * 400;

    f32x2 acc[8];
    #pragma unroll
    for (int j = 0; j < 8; ++j) acc[j] = (f32x2)(0.f);

    #pragma unroll 4
    for (int k = 0; k < 400; ++k) {
        f32x2 hv = *(const f32x2*)&ht[(size_t)k * nc + img];
        #pragma unroll
        for (int j = 0; j < 8; ++j)
            acc[j] += hv * wb[j * 400 + k];   // uniform w -> s_load
    }
    #pragma unroll
    for (int j = 0; j < 8; ++j) {
        int o = og * 8 + j;
        float b = f1b[o];
        f32x2 o2;
        o2.x = fmaxf(acc[j].x + b, 0.f);
        o2.y = fmaxf(acc[j].y + b, 0.f);
        *(f32x2*)&a1t[(size_t)o * nc + img] = o2;
    }
}

// fc2: a2t[o][n] = relu(sum_k a1t[k][n]*f2w[o][k] + b). 7 outs x 12 groups.
__global__ __launch_bounds__(256) void fc2_bt(
    const float* __restrict__ a1t, const float* __restrict__ f2w,
    const float* __restrict__ f2b, float* __restrict__ a2t, int nc)
{
    const int newid = xcd_swizzle(blockIdx.x, gridDim.x);
    const int grp = newid / 12, og = newid - grp * 12;
    const int img = grp * 512 + threadIdx.x * 2;
    const float* wb = f2w + og * 7 * 120;

    f32x2 acc[7];
    #pragma unroll
    for (int j = 0; j < 7; ++j) acc[j] = (f32x2)(0.f);

    #pragma unroll 4
    for (int k = 0; k < 120; ++k) {
        f32x2 hv = *(const f32x2*)&a1t[(size_t)k * nc + img];
        #pragma unroll
        for (int j = 0; j < 7; ++j)
            acc[j] += hv * wb[j * 120 + k];
    }
    #pragma unroll
    for (int j = 0; j < 7; ++j) {
        int o = og * 7 + j;
        float b = f2b[o];
        f32x2 o2;
        o2.x = fmaxf(acc[j].x + b, 0.f);
        o2.y = fmaxf(acc[j].y + b, 0.f);
        *(f32x2*)&a2t[(size_t)o * nc + img] = o2;
    }
}

// fc3 (no relu): embt[o][n0+n] = sum_k a2t[k][n]*f3w[o][k] + b.
// embt is the FULL-N buffer [64][Ntot]; chunk writes at offset n0.
__global__ __launch_bounds__(256) void fc3_bt(
    const float* __restrict__ a2t, const float* __restrict__ f3w,
    const float* __restrict__ f3b, float* __restrict__ embt,
    int nc, int Ntot, int n0)
{
    const int newid = xcd_swizzle(blockIdx.x, gridDim.x);
    const int grp = newid / 8, og = newid - grp * 8;
    const int limg = grp * 512 + threadIdx.x * 2;
    const float* wb = f3w + og * 8 * 84;

    f32x2 acc[8];
    #pragma unroll
    for (int j = 0; j < 8; ++j) acc[j] = (f32x2)(0.f);

    #pragma unroll 4
    for (int k = 0; k < 84; ++k) {
        f32x2 hv = *(const f32x2*)&a2t[(size_t)k * nc + limg];
        #pragma unroll
        for (int j = 0; j < 8; ++j)
            acc[j] += hv * wb[j * 84 + k];
    }
    #pragma unroll
    for (int j = 0; j < 8; ++j) {
        int o = og * 8 + j;
        float b = f3b[o];
        f32x2 o2 = acc[j] + b;
        *(f32x2*)&embt[(size_t)o * Ntot + n0 + limg] = o2;
    }
}

// Head: thread = image. Serial 64-wide softmax in registers; proto via
// uniform s_load of embt[o][0]. Stores 64 consecutive floats per thread.
__global__ __launch_bounds__(256) void proto_head_t(
    const float* __restrict__ embt, float* __restrict__ out, int N)
{
    const int img = blockIdx.x * 256 + threadIdx.x;
    float v[64];
    float m = -1e30f;
    #pragma unroll
    for (int o = 0; o < 64; ++o) {
        v[o] = embt[(size_t)o * N + img];
        m = fmaxf(m, v[o]);
    }
    float s = 0.f;
    #pragma unroll
    for (int o = 0; o < 64; ++o) {
        v[o] = __expf(v[o] - m);
        s += v[o];
    }
    float inv = __frcp_rn(s);
    #pragma unroll
    for (int o = 0; o < 64; o += 4) {
        float4 r;
        r.x = fabsf(v[o+0] * inv - embt[(size_t)(o+0) * N] * 0.2f);
        r.y = fabsf(v[o+1] * inv - embt[(size_t)(o+1) * N] * 0.2f);
        r.z = fabsf(v[o+2] * inv - embt[(size_t)(o+2) * N] * 0.2f);
        r.w = fabsf(v[o+3] * inv - embt[(size_t)(o+3) * N] * 0.2f);
        *(float4*)&out[(size_t)img * 64 + o] = r;
    }
}

extern "C" void kernel_launch(void* const* d_in, const int* in_sizes, int n_in,
                              void* d_out, int out_size, void* d_ws, size_t ws_size,
                              hipStream_t stream)
{
    const float* x   = (const float*)d_in[0];
    const float* c1w = (const float*)d_in[1];
    const float* c1b = (const float*)d_in[2];
    const float* c2w = (const float*)d_in[3];
    const float* c2b = (const float*)d_in[4];
    const float* f1w = (const float*)d_in[5];
    const float* f1b = (const float*)d_in[6];
    const float* f2w = (const float*)d_in[7];
    const float* f2b = (const float*)d_in[8];
    const float* f3w = (const float*)d_in[9];
    const float* f3b = (const float*)d_in[10];
    float* out = (float*)d_out;

    const int N = in_sizes[0] / 784;          // 20480
    float* base = (float*)d_ws;

    // Region A: xt[1024][nc] -> reused as ht[400][nc]
    // Region B: p1t[1176][nc] -> reused as a1t[120][nc] + a2t[84][nc]
    // embt[64][N] persistent.  bytes = 8800nc + 256N
    int c = 40;
    const int cands[] = {1, 2, 4, 5, 8, 10, 20, 40};
    for (int k = 0; k < 8; ++k) {
        int cd = cands[k];
        if (N % cd) continue;
        int ncq = N / cd;
        if (ncq % 512) continue;
        size_t need = (size_t)8800 * ncq + (size_t)256 * N;
        if (need <= ws_size) { c = cd; break; }
    }
    const int nc = N / c;

    float* xt   = base;                        // [1024][nc] padded images
    float* p1t  = base + (size_t)1024 * nc;    // [1176][nc]
    float* ht_  = base;                        // [400][nc]  (over xt)
    float* a1t  = p1t;                         // [120][nc]  (over p1t)
    float* a2t  = p1t + (size_t)120 * nc;      // [84][nc]
    float* embt = base + (size_t)2200 * nc;    // [64][N]

    for (int k = 0; k < c; ++k) {
        int n0 = k * nc;
        transpose_x<<<dim3(16, nc / 64), 256, 0, stream>>>(
            x + (size_t)n0 * 784, xt, nc);
        conv1_bt<<<196 * (nc / 512), 256, 0, stream>>>(
            xt, c1w, c1b, p1t, nc);
        conv2_bt<<<50 * (nc / 512), 256, 0, stream>>>(
            p1t, c2w, c2b, ht_, nc);
        fc1_bt<<<15 * (nc / 512), 256, 0, stream>>>(
            ht_, f1w, f1b, a1t, nc);
        fc2_bt<<<12 * (nc / 512), 256, 0, stream>>>(
            a1t, f2w, f2b, a2t, nc);
        fc3_bt<<<8 * (nc / 512), 256, 0, stream>>>(
            a2t, f3w, f3b, embt, nc, N, n0);
    }
    proto_head_t<<<N / 256, 256, 0, stream>>>(embt, out, N);
}

// Round 17
// 270.410 us; speedup vs baseline: 1.0380x; 1.0380x over previous
//
#include <hip/hip_runtime.h>

// ---------------------------------------------------------------------------
// Batch-inner LeNet: lane = image, activations in [feature][N] layout.
// CONSOLIDATION = R15 (measured best, 269.0 us).
// Ladder: 586 -> 371 (batch-inner) -> 344 (XCD swizzle) -> 324 (scalar-pipe
// weights) -> 297 (fc batch-inner) -> 282 (conv2 oc-split) -> 269 (f32x2).
// conv2 = ~84% of measured sustained fp32 VALU floor (m07: 103 TF);
// MFMA restructurings (R12/R13) and pk-FMA (R15-auto/R16-asm) all
// neutral-to-negative -> fp32 vector path ceiling.
// ---------------------------------------------------------------------------

typedef __attribute__((ext_vector_type(2))) float f32x2;

__device__ __forceinline__ int xcd_swizzle(int orig, int nwg) {
    // m204 bijective: xcd = orig%8 gets a contiguous newid range.
    int xcd = orig & 7, q = nwg >> 3, r = nwg & 7;
    int base = (xcd < r) ? xcd * (q + 1) : r * (q + 1) + (xcd - r) * q;
    return base + (orig >> 3);
}

// Transpose x[nc,784] -> xt[1024,nc] (zero-padded 32x32 image layout).
// grid = (16, nc/64).
__global__ __launch_bounds__(256) void transpose_x(
    const float* __restrict__ x, float* __restrict__ xt, int nc)
{
    __shared__ float t[64][65];
    const int tx = threadIdx.x & 63, ty = threadIdx.x >> 6;  // ty 0..3
    const int p0 = blockIdx.x * 64, n0 = blockIdx.y * 64;
    #pragma unroll
    for (int rr = 0; rr < 16; ++rr) {
        int nl = rr * 4 + ty;
        int pp = p0 + tx;              // padded pixel 0..1023
        int pr = pp >> 5, pc = pp & 31;
        float v = 0.f;
        if (pr >= 2 && pr < 30 && pc >= 2 && pc < 30)
            v = x[(size_t)(n0 + nl) * 784 + (pr - 2) * 28 + (pc - 2)];
        t[tx][nl] = v;
    }
    __syncthreads();
    #pragma unroll
    for (int rr = 0; rr < 16; ++rr) {
        int pl = rr * 4 + ty;
        xt[(size_t)(p0 + pl) * nc + n0 + tx] = t[pl][tx];
    }
}

// conv1(pad2)+relu+pool. Flat grid = 196*(nc/512); 2 consecutive images per
// thread (f32x2). Weights via scalar pipe.
__global__ __launch_bounds__(256, 1) void conv1_bt(
    const float* __restrict__ xt, const float* __restrict__ c1w,
    const float* __restrict__ c1b, float* __restrict__ p1t, int nc)
{
    const int newid = xcd_swizzle(blockIdx.x, gridDim.x);
    const int grp = newid / 196, pos = newid - grp * 196;
    const int py = pos / 14, px = pos - py * 14;
    const int img = grp * 512 + threadIdx.x * 2;
    const int pbase = (2 * py) * 32 + 2 * px; // top-left of 6x6 in padded img

    f32x2 p[36];
    #pragma unroll
    for (int r = 0; r < 6; ++r)
        #pragma unroll
        for (int cc = 0; cc < 6; ++cc)
            p[r * 6 + cc] =
                *(const f32x2*)&xt[(size_t)(pbase + r * 32 + cc) * nc + img];

    #pragma unroll
    for (int ch = 0; ch < 6; ++ch) {
        float w[25];
        const float* wp = c1w + ch * 25;     // uniform -> s_load
        #pragma unroll
        for (int k = 0; k < 25; ++k) w[k] = wp[k];
        float b = c1b[ch];
        f32x2 m01 = (f32x2)(-1e30f);
        #pragma unroll
        for (int dy = 0; dy < 2; ++dy)
        #pragma unroll
        for (int dx = 0; dx < 2; ++dx) {
            f32x2 a = (f32x2)(b);
            #pragma unroll
            for (int ky = 0; ky < 5; ++ky)
            #pragma unroll
            for (int kx = 0; kx < 5; ++kx)
                a += p[(dy + ky) * 6 + dx + kx] * w[ky * 5 + kx];
            m01.x = fmaxf(m01.x, a.x);
            m01.y = fmaxf(m01.y, a.y);
        }
        f32x2 o2;
        o2.x = fmaxf(m01.x, 0.f);
        o2.y = fmaxf(m01.y, 0.f);
        *(f32x2*)&p1t[(size_t)(ch * 196 + pos) * nc + img] = o2;
    }
}

// conv2(valid)+relu+pool: 2 images/thread (f32x2), 8 oc/block (pass in
// blockIdx). Flat grid = 50*(nc/512), XCD-swizzled (group window 2.4 MB
// <= 4 MB L2). Feature order ch*25 + qy*5 + qx.
__global__ __launch_bounds__(256, 1) void conv2_bt(
    const float* __restrict__ p1t, const float* __restrict__ c2w,
    const float* __restrict__ c2b, float* __restrict__ ht, int nc)
{
    const int newid = xcd_swizzle(blockIdx.x, gridDim.x);
    const int grp = newid / 50, rem = newid - grp * 50;
    const int pass = rem / 25, pos = rem - pass * 25;
    const int qy = pos / 5, qx = pos - qy * 5;
    const int img = grp * 512 + threadIdx.x * 2;
    const int y0 = 2 * qy, x0 = 2 * qx;

    f32x2 acc[32];                      // [o8][quad], 2 imgs packed
    #pragma unroll
    for (int i = 0; i < 32; ++i) acc[i] = (f32x2)(0.f);

    #pragma unroll 1
    for (int ci = 0; ci < 6; ++ci) {
        f32x2 pa[36];
        #pragma unroll
        for (int r = 0; r < 6; ++r)
            #pragma unroll
            for (int cc = 0; cc < 6; ++cc)
                pa[r * 6 + cc] = *(const f32x2*)
                    &p1t[(size_t)(ci * 196 + (y0 + r) * 14 + x0 + cc) * nc + img];
        #pragma unroll
        for (int o8 = 0; o8 < 8; ++o8) {
            float w[25];
            const float* wp = c2w + ((pass * 8 + o8) * 6 + ci) * 25;
            #pragma unroll
            for (int k = 0; k < 25; ++k) w[k] = wp[k];
            #pragma unroll
            for (int ky = 0; ky < 5; ++ky)
            #pragma unroll
            for (int kx = 0; kx < 5; ++kx) {
                float ww = w[ky * 5 + kx];
                acc[o8*4+0] += pa[ky*6+kx]       * ww;
                acc[o8*4+1] += pa[ky*6+kx+1]     * ww;
                acc[o8*4+2] += pa[(ky+1)*6+kx]   * ww;
                acc[o8*4+3] += pa[(ky+1)*6+kx+1] * ww;
            }
        }
    }
    #pragma unroll
    for (int o8 = 0; o8 < 8; ++o8) {
        int oc = pass * 8 + o8;
        float b = c2b[oc];
        float mx = fmaxf(fmaxf(acc[o8*4+0].x, acc[o8*4+1].x),
                         fmaxf(acc[o8*4+2].x, acc[o8*4+3].x)) + b;
        float my = fmaxf(fmaxf(acc[o8*4+0].y, acc[o8*4+1].y),
                         fmaxf(acc[o8*4+2].y, acc[o8*4+3].y)) + b;
        f32x2 o2;
        o2.x = fmaxf(mx, 0.f);
        o2.y = fmaxf(my, 0.f);
        *(f32x2*)&ht[(size_t)(oc * 25 + pos) * nc + img] = o2;
    }
}

// fc1: a1t[o][n] = relu(sum_k ht[k][n]*f1w[o][k] + b). 2 img/thread (f32x2),
// 8 outs/block-group. Flat grid = 15*(nc/512), XCD-swizzled.
__global__ __launch_bounds__(256) void fc1_bt(
    const float* __restrict__ ht, const float* __restrict__ f1w,
    const float* __restrict__ f1b, float* __restrict__ a1t, int nc)
{
    const int newid = xcd_swizzle(blockIdx.x, gridDim.x);
    const int grp = newid / 15, og = newid - grp * 15;
    const int img = grp * 512 + threadIdx.x * 2;
    const float* wb = f1w + og * 8 * 400;

    f32x2 acc[8];
    #pragma unroll
    for (int j = 0; j < 8; ++j) acc[j] = (f32x2)(0.f);

    #pragma unroll 4
    for (int k = 0; k < 400; ++k) {
        f32x2 hv = *(const f32x2*)&ht[(size_t)k * nc + img];
        #pragma unroll
        for (int j = 0; j < 8; ++j)
            acc[j] += hv * wb[j * 400 + k];   // uniform w -> s_load
    }
    #pragma unroll
    for (int j = 0; j < 8; ++j) {
        int o = og * 8 + j;
        float b = f1b[o];
        f32x2 o2;
        o2.x = fmaxf(acc[j].x + b, 0.f);
        o2.y = fmaxf(acc[j].y + b, 0.f);
        *(f32x2*)&a1t[(size_t)o * nc + img] = o2;
    }
}

// fc2: a2t[o][n] = relu(sum_k a1t[k][n]*f2w[o][k] + b). 7 outs x 12 groups.
__global__ __launch_bounds__(256) void fc2_bt(
    const float* __restrict__ a1t, const float* __restrict__ f2w,
    const float* __restrict__ f2b, float* __restrict__ a2t, int nc)
{
    const int newid = xcd_swizzle(blockIdx.x, gridDim.x);
    const int grp = newid / 12, og = newid - grp * 12;
    const int img = grp * 512 + threadIdx.x * 2;
    const float* wb = f2w + og * 7 * 120;

    f32x2 acc[7];
    #pragma unroll
    for (int j = 0; j < 7; ++j) acc[j] = (f32x2)(0.f);

    #pragma unroll 4
    for (int k = 0; k < 120; ++k) {
        f32x2 hv = *(const f32x2*)&a1t[(size_t)k * nc + img];
        #pragma unroll
        for (int j = 0; j < 7; ++j)
            acc[j] += hv * wb[j * 120 + k];
    }
    #pragma unroll
    for (int j = 0; j < 7; ++j) {
        int o = og * 7 + j;
        float b = f2b[o];
        f32x2 o2;
        o2.x = fmaxf(acc[j].x + b, 0.f);
        o2.y = fmaxf(acc[j].y + b, 0.f);
        *(f32x2*)&a2t[(size_t)o * nc + img] = o2;
    }
}

// fc3 (no relu): embt[o][n0+n] = sum_k a2t[k][n]*f3w[o][k] + b.
// embt is the FULL-N buffer [64][Ntot]; chunk writes at offset n0.
__global__ __launch_bounds__(256) void fc3_bt(
    const float* __restrict__ a2t, const float* __restrict__ f3w,
    const float* __restrict__ f3b, float* __restrict__ embt,
    int nc, int Ntot, int n0)
{
    const int newid = xcd_swizzle(blockIdx.x, gridDim.x);
    const int grp = newid / 8, og = newid - grp * 8;
    const int limg = grp * 512 + threadIdx.x * 2;
    const float* wb = f3w + og * 8 * 84;

    f32x2 acc[8];
    #pragma unroll
    for (int j = 0; j < 8; ++j) acc[j] = (f32x2)(0.f);

    #pragma unroll 4
    for (int k = 0; k < 84; ++k) {
        f32x2 hv = *(const f32x2*)&a2t[(size_t)k * nc + limg];
        #pragma unroll
        for (int j = 0; j < 8; ++j)
            acc[j] += hv * wb[j * 84 + k];
    }
    #pragma unroll
    for (int j = 0; j < 8; ++j) {
        int o = og * 8 + j;
        float b = f3b[o];
        f32x2 o2 = acc[j] + b;
        *(f32x2*)&embt[(size_t)o * Ntot + n0 + limg] = o2;
    }
}

// Head: thread = image. Serial 64-wide softmax in registers; proto via
// uniform s_load of embt[o][0]. Stores 64 consecutive floats per thread.
__global__ __launch_bounds__(256) void proto_head_t(
    const float* __restrict__ embt, float* __restrict__ out, int N)
{
    const int img = blockIdx.x * 256 + threadIdx.x;
    float v[64];
    float m = -1e30f;
    #pragma unroll
    for (int o = 0; o < 64; ++o) {
        v[o] = embt[(size_t)o * N + img];
        m = fmaxf(m, v[o]);
    }
    float s = 0.f;
    #pragma unroll
    for (int o = 0; o < 64; ++o) {
        v[o] = __expf(v[o] - m);
        s += v[o];
    }
    float inv = __frcp_rn(s);
    #pragma unroll
    for (int o = 0; o < 64; o += 4) {
        float4 r;
        r.x = fabsf(v[o+0] * inv - embt[(size_t)(o+0) * N] * 0.2f);
        r.y = fabsf(v[o+1] * inv - embt[(size_t)(o+1) * N] * 0.2f);
        r.z = fabsf(v[o+2] * inv - embt[(size_t)(o+2) * N] * 0.2f);
        r.w = fabsf(v[o+3] * inv - embt[(size_t)(o+3) * N] * 0.2f);
        *(float4*)&out[(size_t)img * 64 + o] = r;
    }
}

extern "C" void kernel_launch(void* const* d_in, const int* in_sizes, int n_in,
                              void* d_out, int out_size, void* d_ws, size_t ws_size,
                              hipStream_t stream)
{
    const float* x   = (const float*)d_in[0];
    const float* c1w = (const float*)d_in[1];
    const float* c1b = (const float*)d_in[2];
    const float* c2w = (const float*)d_in[3];
    const float* c2b = (const float*)d_in[4];
    const float* f1w = (const float*)d_in[5];
    const float* f1b = (const float*)d_in[6];
    const float* f2w = (const float*)d_in[7];
    const float* f2b = (const float*)d_in[8];
    const float* f3w = (const float*)d_in[9];
    const float* f3b = (const float*)d_in[10];
    float* out = (float*)d_out;

    const int N = in_sizes[0] / 784;          // 20480
    float* base = (float*)d_ws;

    // Region A: xt[1024][nc] -> reused as ht[400][nc]
    // Region B: p1t[1176][nc] -> reused as a1t[120][nc] + a2t[84][nc]
    // embt[64][N] persistent.  bytes = 8800nc + 256N
    int c = 40;
    const int cands[] = {1, 2, 4, 5, 8, 10, 20, 40};
    for (int k = 0; k < 8; ++k) {
        int cd = cands[k];
        if (N % cd) continue;
        int ncq = N / cd;
        if (ncq % 512) continue;
        size_t need = (size_t)8800 * ncq + (size_t)256 * N;
        if (need <= ws_size) { c = cd; break; }
    }
    const int nc = N / c;

    float* xt   = base;                        // [1024][nc] padded images
    float* p1t  = base + (size_t)1024 * nc;    // [1176][nc]
    float* ht_  = base;                        // [400][nc]  (over xt)
    float* a1t  = p1t;                         // [120][nc]  (over p1t)
    float* a2t  = p1t + (size_t)120 * nc;      // [84][nc]
    float* embt = base + (size_t)2200 * nc;    // [64][N]

    for (int k = 0; k < c; ++k) {
        int n0 = k * nc;
        transpose_x<<<dim3(16, nc / 64), 256, 0, stream>>>(
            x + (size_t)n0 * 784, xt, nc);
        conv1_bt<<<196 * (nc / 512), 256, 0, stream>>>(
            xt, c1w, c1b, p1t, nc);
        conv2_bt<<<50 * (nc / 512), 256, 0, stream>>>(
            p1t, c2w, c2b, ht_, nc);
        fc1_bt<<<15 * (nc / 512), 256, 0, stream>>>(
            ht_, f1w, f1b, a1t, nc);
        fc2_bt<<<12 * (nc / 512), 256, 0, stream>>>(
            a1t, f2w, f2b, a2t, nc);
        fc3_bt<<<8 * (nc / 512), 256, 0, stream>>>(
            a2t, f3w, f3b, embt, nc, N, n0);
    }
    proto_head_t<<<N / 256, 256, 0, stream>>>(embt, out, N);
}